// Round 1
// baseline (262.925 us; speedup 1.0000x reference)
//
#include <hip/hip_runtime.h>

#define DIM 4096
#define BLK 256

// ---------- kernel 1: token-mix vector prep ----------
__global__ void __launch_bounds__(BLK) vecprep_kernel(
    const float* __restrict__ x, const float* __restrict__ sxx,
    const float* __restrict__ tmk, const float* __restrict__ tmv,
    const float* __restrict__ tmr,
    float* __restrict__ xk, float* __restrict__ xv, float* __restrict__ xr) {
  int i = blockIdx.x * BLK + threadIdx.x;
  float xi = x[i], si = sxx[i];
  float mk = tmk[i], mv = tmv[i], mr = tmr[i];
  xk[i] = xi * mk + si * (1.0f - mk);
  xv[i] = xi * mv + si * (1.0f - mv);
  xr[i] = xi * mr + si * (1.0f - mr);
}

// ---------- kernel 2: fused 3-way matvec (one block per row) ----------
__global__ void __launch_bounds__(BLK) matvec3_kernel(
    const float* __restrict__ wr, const float* __restrict__ wk,
    const float* __restrict__ wv,
    const float* __restrict__ xr, const float* __restrict__ xk,
    const float* __restrict__ xv,
    float* __restrict__ rr, float* __restrict__ k, float* __restrict__ v) {
  const int row = blockIdx.x;
  const int t = threadIdx.x;
  const float4* wr4 = (const float4*)(wr + (size_t)row * DIM);
  const float4* wk4 = (const float4*)(wk + (size_t)row * DIM);
  const float4* wv4 = (const float4*)(wv + (size_t)row * DIM);
  const float4* xr4 = (const float4*)xr;
  const float4* xk4 = (const float4*)xk;
  const float4* xv4 = (const float4*)xv;
  float sr = 0.f, sk = 0.f, sv = 0.f;
#pragma unroll
  for (int j = 0; j < DIM / 4 / BLK; ++j) {   // 4 iterations
    int idx = t + j * BLK;
    float4 a = wr4[idx]; float4 b = xr4[idx];
    sr += a.x * b.x + a.y * b.y + a.z * b.z + a.w * b.w;
    float4 c = wk4[idx]; float4 d = xk4[idx];
    sk += c.x * d.x + c.y * d.y + c.z * d.z + c.w * d.w;
    float4 e = wv4[idx]; float4 f = xv4[idx];
    sv += e.x * f.x + e.y * f.y + e.z * f.z + e.w * f.w;
  }
  // wave(64) shuffle reduce
  for (int off = 32; off > 0; off >>= 1) {
    sr += __shfl_down(sr, off);
    sk += __shfl_down(sk, off);
    sv += __shfl_down(sv, off);
  }
  __shared__ float red[4][3];
  int wave = t >> 6, lane = t & 63;
  if (lane == 0) { red[wave][0] = sr; red[wave][1] = sk; red[wave][2] = sv; }
  __syncthreads();
  if (t == 0) {
    float a = 0.f, b = 0.f, c = 0.f;
    for (int w = 0; w < 4; ++w) { a += red[w][0]; b += red[w][1]; c += red[w][2]; }
    rr[row] = a; k[row] = b; v[row] = c;
  }
}

// ---------- kernel 3: elementwise WKV + state update ----------
__global__ void __launch_bounds__(BLK) wkv_kernel(
    const float* __restrict__ x, const float* __restrict__ aa,
    const float* __restrict__ bb, const float* __restrict__ pp,
    const float* __restrict__ t_decay, const float* __restrict__ t_first,
    const float* __restrict__ k, const float* __restrict__ v,
    const float* __restrict__ rr,
    float* __restrict__ rab, float* __restrict__ out_x,
    float* __restrict__ out_aa, float* __restrict__ out_bb,
    float* __restrict__ out_pp) {
  int i = blockIdx.x * BLK + threadIdx.x;
  float kk = k[i], vv = v[i];
  float r = 1.0f / (1.0f + expf(-rr[i]));
  float ppi = pp[i], aai = aa[i], bbi = bb[i];
  // output path (bonus t_first)
  float ww = t_first[i] + kk;
  float p = fmaxf(ppi, ww);
  float e1 = expf(ppi - p), e2 = expf(ww - p);
  float a = e1 * aai + e2 * vv;
  float b = e1 * bbi + e2;
  rab[i] = r * (a / b);
  // state update path (decay)
  float ww2 = ppi + t_decay[i];
  float p2 = fmaxf(ww2, kk);
  float e1b = expf(ww2 - p2), e2b = expf(kk - p2);
  out_x[i] = x[i];
  out_aa[i] = e1b * aai + e2b * vv;
  out_bb[i] = e1b * bbi + e2b;
  out_pp[i] = p2;
}

// ---------- kernel 4: output matvec ----------
__global__ void __launch_bounds__(BLK) matvec1_kernel(
    const float* __restrict__ w, const float* __restrict__ xin,
    float* __restrict__ y) {
  const int row = blockIdx.x;
  const int t = threadIdx.x;
  const float4* w4 = (const float4*)(w + (size_t)row * DIM);
  const float4* x4 = (const float4*)xin;
  float s = 0.f;
#pragma unroll
  for (int j = 0; j < DIM / 4 / BLK; ++j) {
    int idx = t + j * BLK;
    float4 a = w4[idx]; float4 b = x4[idx];
    s += a.x * b.x + a.y * b.y + a.z * b.z + a.w * b.w;
  }
  for (int off = 32; off > 0; off >>= 1) s += __shfl_down(s, off);
  __shared__ float red[4];
  int wave = t >> 6, lane = t & 63;
  if (lane == 0) red[wave] = s;
  __syncthreads();
  if (t == 0) y[row] = red[0] + red[1] + red[2] + red[3];
}

extern "C" void kernel_launch(void* const* d_in, const int* in_sizes, int n_in,
                              void* d_out, int out_size, void* d_ws, size_t ws_size,
                              hipStream_t stream) {
  const float* x       = (const float*)d_in[0];
  const float* sxx     = (const float*)d_in[1];
  const float* aa      = (const float*)d_in[2];
  const float* bb      = (const float*)d_in[3];
  const float* pp      = (const float*)d_in[4];
  const float* w_key   = (const float*)d_in[5];
  const float* w_val   = (const float*)d_in[6];
  const float* w_rec   = (const float*)d_in[7];
  const float* w_out   = (const float*)d_in[8];
  const float* t_decay = (const float*)d_in[9];
  const float* t_first = (const float*)d_in[10];
  const float* t_mix_k = (const float*)d_in[11];
  const float* t_mix_v = (const float*)d_in[12];
  const float* t_mix_r = (const float*)d_in[13];

  float* out    = (float*)d_out;
  float* y      = out;            // output 0
  float* out_x  = out + DIM;      // output 1 (new state_xx = x)
  float* out_aa = out + 2 * DIM;  // output 2
  float* out_bb = out + 3 * DIM;  // output 3
  float* out_pp = out + 4 * DIM;  // output 4

  float* ws  = (float*)d_ws;
  float* xk  = ws;
  float* xv  = ws + DIM;
  float* xr  = ws + 2 * DIM;
  float* k   = ws + 3 * DIM;
  float* v   = ws + 4 * DIM;
  float* rr  = ws + 5 * DIM;
  float* rab = ws + 6 * DIM;

  vecprep_kernel<<<DIM / BLK, BLK, 0, stream>>>(x, sxx, t_mix_k, t_mix_v, t_mix_r,
                                                xk, xv, xr);
  matvec3_kernel<<<DIM, BLK, 0, stream>>>(w_rec, w_key, w_val, xr, xk, xv,
                                          rr, k, v);
  wkv_kernel<<<DIM / BLK, BLK, 0, stream>>>(x, aa, bb, pp, t_decay, t_first,
                                            k, v, rr, rab, out_x, out_aa,
                                            out_bb, out_pp);
  matvec1_kernel<<<DIM, BLK, 0, stream>>>(w_out, rab, y);
}

// Round 2
// 258.932 us; speedup vs baseline: 1.0154x; 1.0154x over previous
//
#include <hip/hip_runtime.h>

#define DIM 4096
#define BLK 256
#define ROWS 4   // rows per block; grid = DIM/ROWS = 1024 blocks

__device__ __forceinline__ float dot4(float4 a, float4 b) {
  return a.x * b.x + a.y * b.y + a.z * b.z + a.w * b.w;
}

// token-mix: x*m + s*(1-m) == s + (x-s)*m
__device__ __forceinline__ float4 mix4(float4 xi, float4 si, float4 m) {
  float4 r;
  r.x = fmaf(xi.x - si.x, m.x, si.x);
  r.y = fmaf(xi.y - si.y, m.y, si.y);
  r.z = fmaf(xi.z - si.z, m.z, si.z);
  r.w = fmaf(xi.w - si.w, m.w, si.w);
  return r;
}

// ---------- kernel 1: vecprep + 3-way matvec + WKV epilogue ----------
__global__ void __launch_bounds__(BLK) fused3_kernel(
    const float* __restrict__ x, const float* __restrict__ sxx,
    const float* __restrict__ tmk, const float* __restrict__ tmv,
    const float* __restrict__ tmr,
    const float* __restrict__ wr, const float* __restrict__ wk,
    const float* __restrict__ wv,
    const float* __restrict__ aa, const float* __restrict__ bb,
    const float* __restrict__ pp,
    const float* __restrict__ t_decay, const float* __restrict__ t_first,
    float* __restrict__ rab, float* __restrict__ out_x,
    float* __restrict__ out_aa, float* __restrict__ out_bb,
    float* __restrict__ out_pp) {
  const int t = threadIdx.x;
  const int row0 = blockIdx.x * ROWS;

  const float4* x4 = (const float4*)x;
  const float4* s4 = (const float4*)sxx;
  const float4* mk4 = (const float4*)tmk;
  const float4* mv4 = (const float4*)tmv;
  const float4* mr4 = (const float4*)tmr;

  // per-thread x fragments (registers): indices t + j*BLK, j=0..3
  float4 fxr[4], fxk[4], fxv[4];
#pragma unroll
  for (int j = 0; j < 4; ++j) {
    int idx = t + j * BLK;
    float4 xi = x4[idx], si = s4[idx];
    fxk[j] = mix4(xi, si, mk4[idx]);
    fxv[j] = mix4(xi, si, mv4[idx]);
    fxr[j] = mix4(xi, si, mr4[idx]);
  }

  float accr[ROWS], acck[ROWS], accv[ROWS];
#pragma unroll
  for (int r = 0; r < ROWS; ++r) { accr[r] = acck[r] = accv[r] = 0.f; }

#pragma unroll
  for (int r = 0; r < ROWS; ++r) {
    const float4* wrp = (const float4*)(wr + (size_t)(row0 + r) * DIM);
    const float4* wkp = (const float4*)(wk + (size_t)(row0 + r) * DIM);
    const float4* wvp = (const float4*)(wv + (size_t)(row0 + r) * DIM);
#pragma unroll
    for (int j = 0; j < 4; ++j) {
      int idx = t + j * BLK;
      accr[r] += dot4(wrp[idx], fxr[j]);
      acck[r] += dot4(wkp[idx], fxk[j]);
      accv[r] += dot4(wvp[idx], fxv[j]);
    }
  }

  // reduce 3*ROWS partials across the block
#pragma unroll
  for (int off = 32; off > 0; off >>= 1) {
#pragma unroll
    for (int r = 0; r < ROWS; ++r) {
      accr[r] += __shfl_down(accr[r], off);
      acck[r] += __shfl_down(acck[r], off);
      accv[r] += __shfl_down(accv[r], off);
    }
  }
  __shared__ float red[4][ROWS * 3];
  const int wave = t >> 6, lane = t & 63;
  if (lane == 0) {
#pragma unroll
    for (int r = 0; r < ROWS; ++r) {
      red[wave][r * 3 + 0] = accr[r];
      red[wave][r * 3 + 1] = acck[r];
      red[wave][r * 3 + 2] = accv[r];
    }
  }
  __syncthreads();

  if (t < ROWS) {
    const int row = row0 + t;
    float sr = red[0][t * 3 + 0] + red[1][t * 3 + 0] + red[2][t * 3 + 0] + red[3][t * 3 + 0];
    float sk = red[0][t * 3 + 1] + red[1][t * 3 + 1] + red[2][t * 3 + 1] + red[3][t * 3 + 1];
    float sv = red[0][t * 3 + 2] + red[1][t * 3 + 2] + red[2][t * 3 + 2] + red[3][t * 3 + 2];

    float rsig = 1.0f / (1.0f + expf(-sr));
    float ppi = pp[row], aai = aa[row], bbi = bb[row];
    // output path (bonus t_first)
    float ww = t_first[row] + sk;
    float p = fmaxf(ppi, ww);
    float e1 = expf(ppi - p), e2 = expf(ww - p);
    float a = e1 * aai + e2 * sv;
    float b = e1 * bbi + e2;
    rab[row] = rsig * (a / b);
    // state update path (decay)
    float ww2 = ppi + t_decay[row];
    float p2 = fmaxf(ww2, sk);
    float e1b = expf(ww2 - p2), e2b = expf(sk - p2);
    out_x[row]  = x[row];
    out_aa[row] = e1b * aai + e2b * sv;
    out_bb[row] = e1b * bbi + e2b;
    out_pp[row] = p2;
  }
}

// ---------- kernel 2: y = w_out @ rab ----------
__global__ void __launch_bounds__(BLK) matvec_out_kernel(
    const float* __restrict__ w, const float* __restrict__ xin,
    float* __restrict__ y) {
  const int t = threadIdx.x;
  const int row0 = blockIdx.x * ROWS;
  const float4* x4 = (const float4*)xin;

  float4 fx[4];
#pragma unroll
  for (int j = 0; j < 4; ++j) fx[j] = x4[t + j * BLK];

  float acc[ROWS];
#pragma unroll
  for (int r = 0; r < ROWS; ++r) acc[r] = 0.f;

#pragma unroll
  for (int r = 0; r < ROWS; ++r) {
    const float4* wp = (const float4*)(w + (size_t)(row0 + r) * DIM);
#pragma unroll
    for (int j = 0; j < 4; ++j) acc[r] += dot4(wp[t + j * BLK], fx[j]);
  }

#pragma unroll
  for (int off = 32; off > 0; off >>= 1) {
#pragma unroll
    for (int r = 0; r < ROWS; ++r) acc[r] += __shfl_down(acc[r], off);
  }
  __shared__ float red[4][ROWS];
  const int wave = t >> 6, lane = t & 63;
  if (lane == 0) {
#pragma unroll
    for (int r = 0; r < ROWS; ++r) red[wave][r] = acc[r];
  }
  __syncthreads();
  if (t < ROWS) {
    y[row0 + t] = red[0][t] + red[1][t] + red[2][t] + red[3][t];
  }
}

extern "C" void kernel_launch(void* const* d_in, const int* in_sizes, int n_in,
                              void* d_out, int out_size, void* d_ws, size_t ws_size,
                              hipStream_t stream) {
  const float* x       = (const float*)d_in[0];
  const float* sxx     = (const float*)d_in[1];
  const float* aa      = (const float*)d_in[2];
  const float* bb      = (const float*)d_in[3];
  const float* pp      = (const float*)d_in[4];
  const float* w_key   = (const float*)d_in[5];
  const float* w_val   = (const float*)d_in[6];
  const float* w_rec   = (const float*)d_in[7];
  const float* w_out   = (const float*)d_in[8];
  const float* t_decay = (const float*)d_in[9];
  const float* t_first = (const float*)d_in[10];
  const float* t_mix_k = (const float*)d_in[11];
  const float* t_mix_v = (const float*)d_in[12];
  const float* t_mix_r = (const float*)d_in[13];

  float* out    = (float*)d_out;
  float* y      = out;            // output 0
  float* out_x  = out + DIM;      // output 1 (new state_xx = x)
  float* out_aa = out + 2 * DIM;  // output 2
  float* out_bb = out + 3 * DIM;  // output 3
  float* out_pp = out + 4 * DIM;  // output 4

  float* rab = (float*)d_ws;      // 4096 floats

  fused3_kernel<<<DIM / ROWS, BLK, 0, stream>>>(
      x, sxx, t_mix_k, t_mix_v, t_mix_r, w_rec, w_key, w_val,
      aa, bb, pp, t_decay, t_first,
      rab, out_x, out_aa, out_bb, out_pp);
  matvec_out_kernel<<<DIM / ROWS, BLK, 0, stream>>>(w_out, rab, y);
}